// Round 3
// baseline (1979.588 us; speedup 1.0000x reference)
//
#include <hip/hip_runtime.h>

// out[r*64+ch] = b[ch] + sum_{edges (r,c)} W[ch][c],  r normalized by row.min().
// N = 100000, C = 64, E = 3.2M.
//
// R3: LDS-staged row-bucket binning (full-line 64B flushes, no write amplification)
//     + per-bucket LDS-tile accumulate (ds_add_f32, zero global fp atomics).
// ws layout: flags | Wt[N*64] | gtail[nb] | ovf | recs[nb*cap_b]

#define OVF_MAX (1 << 19)
#define RPB 256       // rows per bucket (lrow fits in 8 bits; col needs <= 17 bits)
#define NB_MAX 400    // static LDS staging sized for nb <= 400 (N <= 102400)
#define SLOTS 32

__global__ void LINK_init_kernel(float* __restrict__ out, const float* __restrict__ b,
                                 int total, int* __restrict__ flags,
                                 int* __restrict__ gtail, int nb) {
    int i = blockIdx.x * blockDim.x + threadIdx.x;
    if (i == 0) { flags[0] = 0; flags[1] = 0x7fffffff; flags[2] = 0x7fffffff; flags[8] = 0; }
    if (i < nb) gtail[i] = 0;
    if (i < total) out[i] = b[i & 63];
}

// Detect int32 vs int64 edge_index; row.min() under both interpretations.
__global__ void LINK_analyze_kernel(const unsigned int* __restrict__ words, int E,
                                    int* __restrict__ flags) {
    long long stride = (long long)gridDim.x * blockDim.x;
    long long i0 = (long long)blockIdx.x * blockDim.x + threadIdx.x;
    long long twoE = 2LL * E;
    unsigned int oddOr = 0u;
    int mn32 = 0x7fffffff, mn64 = 0x7fffffff;
    for (long long i = i0; i < twoE; i += stride) {
        unsigned int w = words[i];
        if (i & 1) oddOr |= w;
        else { int v = (int)w; if (v < mn64) mn64 = v; }
        if (i < E) { int v = (int)w; if (v < mn32) mn32 = v; }
    }
    for (int off = 32; off > 0; off >>= 1) {
        oddOr |= (unsigned int)__shfl_down((int)oddOr, off, 64);
        mn32 = min(mn32, __shfl_down(mn32, off, 64));
        mn64 = min(mn64, __shfl_down(mn64, off, 64));
    }
    if ((threadIdx.x & 63) == 0) {
        if (oddOr) atomicOr(&flags[0], 1);
        atomicMin(&flags[1], mn32);
        atomicMin(&flags[2], mn64);
    }
}

// W [64][N] -> Wt [N][64] via padded LDS tile.
__global__ void LINK_transpose_kernel(const float* __restrict__ W, float* __restrict__ Wt,
                                      int N) {
    __shared__ float tile[64][65];
    int n0 = blockIdx.x * 64;
    int lx = threadIdx.x & 63;
    int ly = threadIdx.x >> 6;
#pragma unroll
    for (int it = 0; it < 16; ++it) {
        int ch = ly + 4 * it;
        float v = 0.0f;
        if (n0 + lx < N) v = W[(size_t)ch * N + (n0 + lx)];
        tile[lx][ch] = v;
    }
    __syncthreads();
#pragma unroll
    for (int it = 0; it < 16; ++it) {
        int nn = ly + 4 * it;
        if (n0 + nn < N) Wt[(size_t)(n0 + nn) * 64 + lx] = tile[nn][lx];
    }
}

// Bin edges into row buckets with LDS staging; flush 16-record (64B) full lines.
__global__ __launch_bounds__(512) void LINK_bin_kernel(
    const unsigned int* __restrict__ words, int E, int N, int nb, int cap_b,
    int* __restrict__ gtail, unsigned int* __restrict__ recs,
    int* __restrict__ ovf, int* __restrict__ flags) {
    __shared__ unsigned int lstage[NB_MAX * SLOTS];
    __shared__ int lcnt[NB_MAX];
    int tid = threadIdx.x;
    int nthreads = blockDim.x;
    for (int k = tid; k < nb; k += nthreads) lcnt[k] = 0;
    __syncthreads();
    int isInt32 = flags[0];
    const int BATCH = 8;
    long long batch_edges = (long long)nthreads * BATCH;  // 4096
    long long nbatches = ((long long)E + batch_edges - 1) / batch_edges;
    int wid = tid >> 6, lane = tid & 63, nw = nthreads >> 6;
    for (long long bt = blockIdx.x; bt < nbatches; bt += gridDim.x) {
        long long e0 = bt * batch_edges + (long long)tid * BATCH;
#pragma unroll
        for (int k = 0; k < BATCH; ++k) {
            long long e = e0 + k;
            if (e >= E) break;
            int r, c;
            if (isInt32) { r = (int)words[e]; c = (int)words[E + e]; }
            else { r = (int)words[2 * e]; c = (int)words[2 * (long long)E + 2 * e]; }
            if ((unsigned)r >= (unsigned)N || (unsigned)c >= (unsigned)N) continue;
            int key = r >> 8;
            unsigned int rec = ((unsigned int)(r & 255) << 17) | (unsigned int)c;
            int pos = atomicAdd(&lcnt[key], 1);
            if (pos < SLOTS) {
                lstage[key * SLOTS + pos] = rec;
            } else {  // rare direct spill
                int g = atomicAdd(&gtail[key], 1);
                if (g < cap_b) recs[(size_t)key * cap_b + g] = rec;
                else {
                    int oi = atomicAdd(&flags[8], 1);
                    if (oi < OVF_MAX) { ovf[2 * oi] = r; ovf[2 * oi + 1] = c; }
                }
            }
        }
        __syncthreads();
        // flush full 64B lines (multiples of 16 records)
        for (int k = wid; k < nb; k += nw) {
            int cnt = lcnt[k]; if (cnt > SLOTS) cnt = SLOTS;
            int f = cnt & ~15;
            if (f > 0) {
                int g = 0;
                if (lane == 0) g = atomicAdd(&gtail[k], f);
                g = __shfl(g, 0);
                if (lane < f) {
                    int gg = g + lane;
                    unsigned int rec = lstage[k * SLOTS + lane];
                    if (gg < cap_b) recs[(size_t)k * cap_b + gg] = rec;
                    else {
                        int oi = atomicAdd(&flags[8], 1);
                        if (oi < OVF_MAX) {
                            ovf[2 * oi] = (k << 8) | (int)(rec >> 17);
                            ovf[2 * oi + 1] = (int)(rec & 0x1FFFF);
                        }
                    }
                }
                int rem = cnt - f;
                unsigned int tmp = 0;
                if (lane < rem) tmp = lstage[k * SLOTS + f + lane];
                if (lane < rem) lstage[k * SLOTS + lane] = tmp;
                if (lane == 0) lcnt[k] = rem;
            }
        }
        __syncthreads();
    }
    // final flush (partial lines, small residual)
    for (int k = wid; k < nb; k += nw) {
        int cnt = lcnt[k]; if (cnt > SLOTS) cnt = SLOTS;
        if (cnt > 0) {
            int g = 0;
            if (lane == 0) g = atomicAdd(&gtail[k], cnt);
            g = __shfl(g, 0);
            if (lane < cnt) {
                int gg = g + lane;
                unsigned int rec = lstage[k * SLOTS + lane];
                if (gg < cap_b) recs[(size_t)k * cap_b + gg] = rec;
                else {
                    int oi = atomicAdd(&flags[8], 1);
                    if (oi < OVF_MAX) {
                        ovf[2 * oi] = (k << 8) | (int)(rec >> 17);
                        ovf[2 * oi + 1] = (int)(rec & 0x1FFFF);
                    }
                }
            }
        }
    }
}

// One block per bucket: 256x64 fp32 LDS tile, stream records, ds_add_f32, one store.
__global__ __launch_bounds__(1024) void LINK_accum_kernel(
    const int* __restrict__ gtail, const unsigned int* __restrict__ recs, int cap_b,
    const float* __restrict__ Wt, const float* __restrict__ bias,
    float* __restrict__ out, const int* __restrict__ flags, int N) {
    __shared__ float tile[RPB * 64];  // 64 KB
    int b = blockIdx.x;
    int tid = threadIdx.x;
    for (int i = tid; i < RPB * 64; i += blockDim.x) tile[i] = 0.0f;
    __syncthreads();
    int len = gtail[b]; if (len > cap_b) len = cap_b;
    int lane = tid & 63, wid = tid >> 6, nw = blockDim.x >> 6;
    const unsigned int* rp = recs + (size_t)b * cap_b;
    for (int base = wid * 64; base < len; base += nw * 64) {
        int cnt = len - base; if (cnt > 64) cnt = 64;
        unsigned int rec = 0;
        if (lane < cnt) rec = rp[base + lane];
#pragma unroll 4
        for (int j = 0; j < cnt; ++j) {
            unsigned int rv = (unsigned int)__shfl((int)rec, j);
            int c = (int)(rv & 0x1FFFF);
            int lr = (int)(rv >> 17);
            float v = Wt[((size_t)c << 6) + lane];
            atomicAdd(&tile[(lr << 6) + lane], v);
        }
    }
    __syncthreads();
    int rmin = flags[0] ? flags[1] : flags[2];
    int row0 = b * RPB;
    for (int i = tid; i < RPB * 64; i += blockDim.x) {
        int lr = i >> 6, ch = i & 63;
        long long orow = (long long)row0 + lr - rmin;
        if (orow >= 0 && orow < N)
            out[(size_t)orow * 64 + ch] = tile[i] + bias[ch];
    }
}

// Cleanup for spilled edges (expected zero on real data).
__global__ void LINK_ovf_kernel(const int* __restrict__ ovf, const int* __restrict__ flags,
                                const float* __restrict__ Wt, float* __restrict__ out,
                                int N) {
    int g = blockIdx.x * blockDim.x + threadIdx.x;
    int w = g >> 6, lane = g & 63;
    int cnt = flags[8]; if (cnt > OVF_MAX) cnt = OVF_MAX;
    if (cnt == 0) return;
    int rmin = flags[0] ? flags[1] : flags[2];
    int nw = (gridDim.x * blockDim.x) >> 6;
    for (int i = w; i < cnt; i += nw) {
        int r = ovf[2 * i] - rmin;
        int c = ovf[2 * i + 1];
        if ((unsigned)r >= (unsigned)N || (unsigned)c >= (unsigned)N) continue;
        atomicAdd(&out[(size_t)r * 64 + lane], Wt[((size_t)c << 6) + lane]);
    }
}

// ---- Fallback (R1): wave-per-edge fp-atomic scatter ----
__global__ void LINK_scatter_kernel(const unsigned int* __restrict__ words, int E,
                                    const float* __restrict__ Wt,
                                    const float* __restrict__ W,
                                    float* __restrict__ out,
                                    const int* __restrict__ flags, int useWt, int N) {
    long long g = (long long)blockIdx.x * blockDim.x + threadIdx.x;
    int e = (int)(g >> 6);
    if (e >= E) return;
    int ch = (int)(g & 63);
    int r, c, rmin;
    if (flags[0]) { r = (int)words[e]; c = (int)words[E + e]; rmin = flags[1]; }
    else { r = (int)words[2LL * e]; c = (int)words[2LL * (E + e)]; rmin = flags[2]; }
    r -= rmin;
    if ((unsigned)r >= (unsigned)N || (unsigned)c >= (unsigned)N) return;
    float v = useWt ? Wt[((size_t)c << 6) + ch] : W[(size_t)ch * N + c];
    atomicAdd(&out[(size_t)r * 64 + ch], v);
}

static inline size_t align256(size_t x) { return (x + 255) & ~(size_t)255; }

extern "C" void kernel_launch(void* const* d_in, const int* in_sizes, int n_in,
                              void* d_out, int out_size, void* d_ws, size_t ws_size,
                              hipStream_t stream) {
    const unsigned int* words = (const unsigned int*)d_in[0];
    const float* W = (const float*)d_in[1];
    const float* b = (const float*)d_in[2];
    float* out = (float*)d_out;

    int E = in_sizes[0] / 2;   // 3,200,000
    int N = in_sizes[1] / 64;  // 100,000
    int total = out_size;      // N*64
    int nb = (N + RPB - 1) / RPB;  // 391

    size_t off_flags = 0;
    size_t off_wt    = align256(off_flags + 256 * sizeof(int));
    size_t off_gtail = align256(off_wt + (size_t)N * 64 * sizeof(float));
    size_t off_ovf   = align256(off_gtail + (size_t)nb * sizeof(int));
    size_t off_recs  = align256(off_ovf + (size_t)OVF_MAX * 2 * sizeof(int));

    int* flags = (int*)((char*)d_ws + off_flags);
    float* Wt  = (float*)((char*)d_ws + off_wt);
    int* gtail = (int*)((char*)d_ws + off_gtail);
    int* ovf   = (int*)((char*)d_ws + off_ovf);
    unsigned int* recs = (unsigned int*)((char*)d_ws + off_recs);

    long long avail = (ws_size > off_recs)
        ? (long long)((ws_size - off_recs) / ((size_t)nb * sizeof(int))) : 0;
    int cap_b = (int)(avail > 16384 ? 16384 : avail);
    bool useBin = (N <= NB_MAX * RPB) && (nb <= NB_MAX) && cap_b >= 10240 &&
                  ((long long)cap_b * nb >= (long long)E + E / 4);

    if (useBin) {
        LINK_init_kernel<<<(total + 255) / 256, 256, 0, stream>>>(out, b, total, flags,
                                                                  gtail, nb);
        LINK_analyze_kernel<<<1024, 256, 0, stream>>>(words, E, flags);
        LINK_transpose_kernel<<<(N + 63) / 64, 256, 0, stream>>>(W, Wt, N);
        LINK_bin_kernel<<<160, 512, 0, stream>>>(words, E, N, nb, cap_b, gtail, recs,
                                                 ovf, flags);
        LINK_accum_kernel<<<nb, 1024, 0, stream>>>(gtail, recs, cap_b, Wt, b, out,
                                                   flags, N);
        LINK_ovf_kernel<<<1024, 256, 0, stream>>>(ovf, flags, Wt, out, N);
    } else {
        size_t wt_bytes = off_wt + (size_t)N * 64 * sizeof(float);
        int useWt = (ws_size >= wt_bytes) ? 1 : 0;
        LINK_init_kernel<<<(total + 255) / 256, 256, 0, stream>>>(out, b, total, flags,
                                                                  gtail, 0);
        LINK_analyze_kernel<<<1024, 256, 0, stream>>>(words, E, flags);
        if (useWt) LINK_transpose_kernel<<<(N + 63) / 64, 256, 0, stream>>>(W, Wt, N);
        long long tthreads = (long long)E * 64;
        LINK_scatter_kernel<<<(int)((tthreads + 255) / 256), 256, 0, stream>>>(
            words, E, Wt, W, out, flags, useWt, N);
    }
}

// Round 4
// 471.626 us; speedup vs baseline: 4.1974x; 4.1974x over previous
//
#include <hip/hip_runtime.h>

// out[r*64+ch] = b[ch] + sum_{edges (r,c)} W[ch][c],  r normalized by row.min().
// N = 100000, C = 64, E = 3.2M.
//
// R4: R2 skeleton with (1) XCD-sharded fill so each shard's cols region (3.2MB)
//     is L2-resident on one XCD (kills the 193MB write amplification), and
//     (2) bf16 Wt + 8-wide unrolled gather (halves gather traffic, doubles MLP).
// ws: flags[256 int] | cur[N int] | Wtb[N*64 bf16] | ovf[OVF_MAX*2 int] | cols[N*64 int]

#define OVF_MAX (1 << 19)
#define CAP 64          // slots per row; Poisson(32) => P(overflow) ~ 1e-7 per row
#define NSHARD 8        // one shard per XCD (blockIdx % 8 round-robin heuristic)

__device__ __forceinline__ float bf16u_to_f(unsigned short u) {
    union { unsigned int i; float f; } x; x.i = ((unsigned int)u) << 16; return x.f;
}

__global__ void LINK_init_kernel(int* __restrict__ cur, int* __restrict__ flags, int N) {
    int i = blockIdx.x * blockDim.x + threadIdx.x;
    if (i == 0) { flags[0] = 0; flags[1] = 0x7fffffff; flags[2] = 0x7fffffff; flags[8] = 0; }
    if (i < N) cur[i] = i << 6;  // i * CAP
}

// Detect int32 vs int64 edge_index; row.min() under both interpretations.
__global__ void LINK_analyze_kernel(const unsigned int* __restrict__ words, int E,
                                    int* __restrict__ flags) {
    long long stride = (long long)gridDim.x * blockDim.x;
    long long i0 = (long long)blockIdx.x * blockDim.x + threadIdx.x;
    long long twoE = 2LL * E;
    unsigned int oddOr = 0u;
    int mn32 = 0x7fffffff, mn64 = 0x7fffffff;
    for (long long i = i0; i < twoE; i += stride) {
        unsigned int w = words[i];
        if (i & 1) oddOr |= w;
        else { int v = (int)w; if (v < mn64) mn64 = v; }
        if (i < E) { int v = (int)w; if (v < mn32) mn32 = v; }
    }
    for (int off = 32; off > 0; off >>= 1) {
        oddOr |= (unsigned int)__shfl_down((int)oddOr, off, 64);
        mn32 = min(mn32, __shfl_down(mn32, off, 64));
        mn64 = min(mn64, __shfl_down(mn64, off, 64));
    }
    if ((threadIdx.x & 63) == 0) {
        if (oddOr) atomicOr(&flags[0], 1);
        atomicMin(&flags[1], mn32);
        atomicMin(&flags[2], mn64);
    }
}

// W [64][N] f32 -> Wtb [N][64] bf16 (RNE) via padded LDS tile.
__global__ void LINK_transpose_kernel(const float* __restrict__ W,
                                      unsigned short* __restrict__ Wtb, int N) {
    __shared__ float tile[64][65];
    int n0 = blockIdx.x * 64;
    int lx = threadIdx.x & 63;
    int ly = threadIdx.x >> 6;
#pragma unroll
    for (int it = 0; it < 16; ++it) {
        int ch = ly + 4 * it;
        float v = 0.0f;
        if (n0 + lx < N) v = W[(size_t)ch * N + (n0 + lx)];
        tile[lx][ch] = v;
    }
    __syncthreads();
#pragma unroll
    for (int it = 0; it < 16; ++it) {
        int nn = ly + 4 * it;
        if (n0 + nn < N) {
            union { float f; unsigned int i; } x; x.f = tile[nn][lx];
            unsigned int u = x.i;
            unsigned int r = (u + 0x7fffu + ((u >> 16) & 1u)) >> 16;  // RNE
            Wtb[((size_t)(n0 + nn) << 6) + lx] = (unsigned short)r;
        }
    }
}

// XCD-sharded CSR fill: block b owns row shard (b & 7). Each shard's cols region
// (12500 rows * 64 slots * 4B = 3.2MB) stays resident in one XCD's L2.
__global__ __launch_bounds__(256) void LINK_fill_kernel(
    const unsigned int* __restrict__ words, int E, int N,
    int* __restrict__ cur, int* __restrict__ cols,
    int* __restrict__ ovf, int* __restrict__ flags) {
    int shard = blockIdx.x & (NSHARD - 1);
    int qb = blockIdx.x >> 3;                 // block index within shard
    int Q = gridDim.x >> 3;                   // blocks per shard
    int rows_per = (N + NSHARD - 1) / NSHARD;
    int rlo = shard * rows_per;
    int rhi = min(N, rlo + rows_per);
    int isInt32 = flags[0];
    long long i0 = (long long)qb * blockDim.x + threadIdx.x;
    long long stride = (long long)Q * blockDim.x;
    for (long long e = i0; e < E; e += stride) {
        int r = isInt32 ? (int)words[e] : (int)words[2 * e];
        if (r < rlo || r >= rhi) continue;
        int c = isInt32 ? (int)words[E + e] : (int)words[2LL * E + 2 * e];
        if ((unsigned)c >= (unsigned)N) continue;
        int pos = atomicAdd(&cur[r], 1);
        if (pos - (r << 6) < CAP) {
            cols[pos] = c;
        } else {
            int oi = atomicAdd(&flags[8], 1);
            if (oi < OVF_MAX) { ovf[2 * oi] = r; ovf[2 * oi + 1] = c; }
        }
    }
}

// One wave per output row; lane = channel. bf16 Wt rows (128B coalesced), fp32 acc,
// 8 independent loads in flight per iteration.
__global__ __launch_bounds__(256) void LINK_gather_kernel(
    const int* __restrict__ cur, const int* __restrict__ cols,
    const unsigned short* __restrict__ Wtb, const float* __restrict__ b,
    float* __restrict__ out, const int* __restrict__ flags, int N) {
    int g = blockIdx.x * blockDim.x + threadIdx.x;
    int row = g >> 6;
    int lane = g & 63;
    if (row >= N) return;
    int rmin = flags[0] ? flags[1] : flags[2];
    float acc = 0.0f;
    long long raw = (long long)row + rmin;
    if (raw >= 0 && raw < N) {
        int base = (int)raw << 6;
        int len = cur[raw] - base;
        if (len > CAP) len = CAP;
        const int* cp = cols + base;
        int j = 0;
        for (; j + 8 <= len; j += 8) {
            int c0 = cp[j + 0], c1 = cp[j + 1], c2 = cp[j + 2], c3 = cp[j + 3];
            int c4 = cp[j + 4], c5 = cp[j + 5], c6 = cp[j + 6], c7 = cp[j + 7];
            unsigned short u0 = Wtb[((size_t)c0 << 6) + lane];
            unsigned short u1 = Wtb[((size_t)c1 << 6) + lane];
            unsigned short u2 = Wtb[((size_t)c2 << 6) + lane];
            unsigned short u3 = Wtb[((size_t)c3 << 6) + lane];
            unsigned short u4 = Wtb[((size_t)c4 << 6) + lane];
            unsigned short u5 = Wtb[((size_t)c5 << 6) + lane];
            unsigned short u6 = Wtb[((size_t)c6 << 6) + lane];
            unsigned short u7 = Wtb[((size_t)c7 << 6) + lane];
            float s01 = bf16u_to_f(u0) + bf16u_to_f(u1);
            float s23 = bf16u_to_f(u2) + bf16u_to_f(u3);
            float s45 = bf16u_to_f(u4) + bf16u_to_f(u5);
            float s67 = bf16u_to_f(u6) + bf16u_to_f(u7);
            acc += (s01 + s23) + (s45 + s67);
        }
        for (; j < len; ++j)
            acc += bf16u_to_f(Wtb[((size_t)cp[j] << 6) + lane]);
    }
    out[((size_t)row << 6) + lane] = acc + b[lane];
}

// Cleanup for spilled edges (expected zero on real data).
__global__ void LINK_ovf_kernel(const int* __restrict__ ovf, const int* __restrict__ flags,
                                const unsigned short* __restrict__ Wtb,
                                float* __restrict__ out, int N) {
    int g = blockIdx.x * blockDim.x + threadIdx.x;
    int w = g >> 6, lane = g & 63;
    int cnt = flags[8]; if (cnt > OVF_MAX) cnt = OVF_MAX;
    if (cnt == 0) return;
    int rmin = flags[0] ? flags[1] : flags[2];
    int nw = (gridDim.x * blockDim.x) >> 6;
    for (int i = w; i < cnt; i += nw) {
        int r = ovf[2 * i] - rmin;
        int c = ovf[2 * i + 1];
        if ((unsigned)r >= (unsigned)N || (unsigned)c >= (unsigned)N) continue;
        atomicAdd(&out[((size_t)r << 6) + lane], bf16u_to_f(Wtb[((size_t)c << 6) + lane]));
    }
}

// ---- Fallback (R1): bias init + wave-per-edge fp-atomic scatter on raw W ----
__global__ void LINK_initout_kernel(float* __restrict__ out, const float* __restrict__ b,
                                    int total, int* __restrict__ flags) {
    int i = blockIdx.x * blockDim.x + threadIdx.x;
    if (i == 0) { flags[0] = 0; flags[1] = 0x7fffffff; flags[2] = 0x7fffffff; }
    if (i < total) out[i] = b[i & 63];
}

__global__ void LINK_scatter_kernel(const unsigned int* __restrict__ words, int E,
                                    const float* __restrict__ W,
                                    float* __restrict__ out,
                                    const int* __restrict__ flags, int N) {
    long long g = (long long)blockIdx.x * blockDim.x + threadIdx.x;
    int e = (int)(g >> 6);
    if (e >= E) return;
    int ch = (int)(g & 63);
    int r, c, rmin;
    if (flags[0]) { r = (int)words[e]; c = (int)words[E + e]; rmin = flags[1]; }
    else { r = (int)words[2LL * e]; c = (int)words[2LL * (E + e)]; rmin = flags[2]; }
    r -= rmin;
    if ((unsigned)r >= (unsigned)N || (unsigned)c >= (unsigned)N) return;
    atomicAdd(&out[((size_t)r << 6) + ch], W[(size_t)ch * N + c]);
}

static inline size_t align256(size_t x) { return (x + 255) & ~(size_t)255; }

extern "C" void kernel_launch(void* const* d_in, const int* in_sizes, int n_in,
                              void* d_out, int out_size, void* d_ws, size_t ws_size,
                              hipStream_t stream) {
    const unsigned int* words = (const unsigned int*)d_in[0];
    const float* W = (const float*)d_in[1];
    const float* b = (const float*)d_in[2];
    float* out = (float*)d_out;

    int E = in_sizes[0] / 2;   // 3,200,000
    int N = in_sizes[1] / 64;  // 100,000
    int total = out_size;      // N*64

    size_t off_flags = 0;
    size_t off_cur   = align256(off_flags + 256 * sizeof(int));
    size_t off_wtb   = align256(off_cur + (size_t)N * sizeof(int));
    size_t off_ovf   = align256(off_wtb + (size_t)N * 64 * sizeof(unsigned short));
    size_t off_cols  = align256(off_ovf + (size_t)OVF_MAX * 2 * sizeof(int));
    size_t need      = off_cols + (size_t)N * CAP * sizeof(int);

    int* flags = (int*)((char*)d_ws + off_flags);
    int* cur   = (int*)((char*)d_ws + off_cur);
    unsigned short* Wtb = (unsigned short*)((char*)d_ws + off_wtb);
    int* ovf   = (int*)((char*)d_ws + off_ovf);
    int* cols  = (int*)((char*)d_ws + off_cols);

    if (ws_size >= need) {
        LINK_init_kernel<<<(N + 255) / 256, 256, 0, stream>>>(cur, flags, N);
        LINK_analyze_kernel<<<1024, 256, 0, stream>>>(words, E, flags);
        LINK_transpose_kernel<<<(N + 63) / 64, 256, 0, stream>>>(W, Wtb, N);
        LINK_fill_kernel<<<2048, 256, 0, stream>>>(words, E, N, cur, cols, ovf, flags);
        long long gthreads = (long long)N * 64;
        LINK_gather_kernel<<<(int)((gthreads + 255) / 256), 256, 0, stream>>>(
            cur, cols, Wtb, b, out, flags, N);
        LINK_ovf_kernel<<<64, 256, 0, stream>>>(ovf, flags, Wtb, out, N);
    } else {
        LINK_initout_kernel<<<(total + 255) / 256, 256, 0, stream>>>(out, b, total, flags);
        LINK_analyze_kernel<<<1024, 256, 0, stream>>>(words, E, flags);
        long long tthreads = (long long)E * 64;
        LINK_scatter_kernel<<<(int)((tthreads + 255) / 256), 256, 0, stream>>>(
            words, E, W, out, flags, N);
    }
}